// Round 16
// baseline (544.102 us; speedup 1.0000x reference)
//
#include <hip/hip_runtime.h>
#include <math.h>

#define NN 1024     // entities
#define HD 128      // hidden dim
#define NH 8        // heads
#define CH 16       // dim per head
#define NLAYERS 3

#define TT 8        // target rows per attention block
#define CHK 256     // j-chunk size staged in LDS (two 128-halves per barrier)
#define ALP 130     // k_edge_w al row stride
#define PBM 4       // k_proj rows per block
#define ABM 2       // k_edge_ab rows per block
#define QSC 0.36067376022224085f   // 0.25 * log2(e)

__device__ __forceinline__ float bf16_to_f32(unsigned short u) {
    union { unsigned int i; float f; } x; x.i = ((unsigned int)u) << 16; return x.f;
}
__device__ __forceinline__ unsigned short f32_to_bf16(float f) {
    union { float f; unsigned int i; } x; x.f = f;
    const unsigned int r = x.i + 0x7FFFu + ((x.i >> 16) & 1u);   // RNE
    return (unsigned short)(r >> 16);
}
__device__ __forceinline__ float bflo(unsigned int u) {
    union { unsigned int i; float f; } x; x.i = u << 16; return x.f;
}
__device__ __forceinline__ float rawf(unsigned int u) {
    union { unsigned int i; float f; } x; x.i = u; return x.f;
}

// ---------------- K1: a = x@W1[:128], b = x@W1[128:] + b1; by==0 also copies x -> xout ----------------
template<int REPS>
__global__ __launch_bounds__(256) void k_edge_ab(
        const float* __restrict__ x, const float* __restrict__ W1,
        const float* __restrict__ b1, float* __restrict__ a, float* __restrict__ b,
        float* __restrict__ xout) {
    __shared__ float xt[HD][ABM];
    __shared__ float red[2][ABM][HD];
    const int r0 = blockIdx.x * ABM;
    const int cb = blockIdx.y;           // 0 -> a, 1 -> b
    const int t  = threadIdx.x;
    #pragma unroll 1
    for (int rep = 0; rep < REPS; ++rep) {
        {
            const float xv = x[(r0 + (t >> 7)) * HD + (t & 127)];
            xt[t & 127][t >> 7] = xv;
            if (cb == 0) xout[(r0 + (t >> 7)) * HD + (t & 127)] = xv;   // fused x init
        }
        __syncthreads();
        const int c = t & 127, g = t >> 7;
        const float* wp = W1 + cb * HD * HD + g * 64 * HD + c;
        const float* xp = &xt[g * 64][0];
        float a0 = 0.f, a1 = 0.f;
        #pragma unroll 8
        for (int kk = 0; kk < 64; ++kk) {
            const float wv = wp[kk * HD];
            const float2 xv = *(const float2*)&xp[kk * ABM];
            a0 = fmaf(xv.x, wv, a0);
            a1 = fmaf(xv.y, wv, a1);
        }
        red[g][0][c] = a0; red[g][1][c] = a1;
        __syncthreads();
        if (t < HD) {
            float* dst = cb ? b : a;
            const float bias = cb ? b1[t] : 0.f;
            #pragma unroll
            for (int r = 0; r < ABM; ++r)
                dst[(r0 + r) * HD + t] = red[0][r][t] + red[1][r][t] + bias;
        }
    }
}

// ---------------- K2: wm[t][s] = bf16( sign(mask) * sigmoid(logit[s][t]) ) ----------------
template<int REPS>
__global__ __launch_bounds__(256) void k_edge_w(
        const float* __restrict__ a, const float* __restrict__ bb,
        const float* __restrict__ W2, const float* __restrict__ b2,
        unsigned short* __restrict__ wm) {
    __shared__ float al[32][ALP];
    __shared__ float bl[16][HD];
    const int t = threadIdx.x;
    const int s0 = blockIdx.x * 32, t0 = blockIdx.y * 16;
    #pragma unroll 1
    for (int rep = 0; rep < REPS; ++rep) {
        for (int ii = t; ii < 2048; ii += 256) {
            const int row = ii >> 6, col = (ii & 63) * 2;
            *(float2*)&al[row][col] = *(const float2*)&a[(s0 + row) * HD + col];
        }
        for (int ii = t; ii < 512; ii += 256) {
            const int row = ii >> 5, col = (ii & 31) * 4;
            *(float4*)&bl[row][col] = *(const float4*)&bb[(t0 + row) * HD + col];
        }
        __syncthreads();
        const int s = t & 31, tt = t >> 5;
        float acc0 = 0.f, acc1 = 0.f;
        #pragma unroll 2
        for (int h4 = 0; h4 < HD; h4 += 4) {
            const float4 w2 = *(const float4*)&W2[h4];
            const float2 avA = *(const float2*)&al[s][h4];
            const float2 avB = *(const float2*)&al[s][h4 + 2];
            const float4 b0v = *(const float4*)&bl[tt][h4];
            const float4 b1v = *(const float4*)&bl[tt + 8][h4];
            acc0 = fmaf(fmaxf(avA.x + b0v.x, 0.f), w2.x, acc0);
            acc0 = fmaf(fmaxf(avA.y + b0v.y, 0.f), w2.y, acc0);
            acc0 = fmaf(fmaxf(avB.x + b0v.z, 0.f), w2.z, acc0);
            acc0 = fmaf(fmaxf(avB.y + b0v.w, 0.f), w2.w, acc0);
            acc1 = fmaf(fmaxf(avA.x + b1v.x, 0.f), w2.x, acc1);
            acc1 = fmaf(fmaxf(avA.y + b1v.y, 0.f), w2.y, acc1);
            acc1 = fmaf(fmaxf(avB.x + b1v.z, 0.f), w2.z, acc1);
            acc1 = fmaf(fmaxf(avB.y + b1v.w, 0.f), w2.w, acc1);
        }
        const float bias = b2[0];
        const float l0 = acc0 + bias, l1 = acc1 + bias;
        const float w0 = 1.f / (1.f + __expf(-l0));
        const float w1 = 1.f / (1.f + __expf(-l1));
        wm[(t0 + tt    ) * NN + s0 + s] = f32_to_bf16((l0 > 0.f) ? w0 : -w0);   // sign encodes mask
        wm[(t0 + tt + 8) * NN + s0 + s] = f32_to_bf16((l1 > 0.f) ? w1 : -w1);
        if (REPS > 1) __syncthreads();   // next rep re-stages al/bl
    }
}

// ---------------- K3: projections q (f32), k,v (bf16) in [h][n][c] + skip (f32) ----------------
template<int REPS>
__global__ __launch_bounds__(256) void k_proj(
        const float* __restrict__ x,
        const float* __restrict__ Wq, const float* __restrict__ bq,
        const float* __restrict__ Wk, const float* __restrict__ bk,
        const float* __restrict__ Wv, const float* __restrict__ bv,
        const float* __restrict__ Wsk, const float* __restrict__ bsk,
        float* __restrict__ q, unsigned short* __restrict__ kb,
        unsigned short* __restrict__ vb, float* __restrict__ skip) {
    __shared__ float xt[HD][PBM];
    __shared__ float red[2][PBM][HD];
    const int r0 = blockIdx.x * PBM;
    const int cb = blockIdx.y;           // 0..3 -> q,k,v,skip
    const int t  = threadIdx.x;
    #pragma unroll 1
    for (int rep = 0; rep < REPS; ++rep) {
        {
            const int r = t >> 6, c2 = (t & 63) * 2;
            const float2 xv = *(const float2*)&x[(r0 + r) * HD + c2];
            xt[c2][r] = xv.x; xt[c2 + 1][r] = xv.y;
        }
        __syncthreads();
        const int c = t & 127, g = t >> 7;
        const float* W = (cb == 0) ? Wq : (cb == 1) ? Wk : (cb == 2) ? Wv : Wsk;
        const float* wp = W + g * 64 * HD + c;
        const float* xp = &xt[g * 64][0];
        float a0 = 0.f, a1 = 0.f, a2 = 0.f, a3 = 0.f;
        #pragma unroll 8
        for (int kk = 0; kk < 64; ++kk) {
            const float wv = wp[kk * HD];
            const float4 xv = *(const float4*)&xp[kk * PBM];
            a0 = fmaf(xv.x, wv, a0);
            a1 = fmaf(xv.y, wv, a1);
            a2 = fmaf(xv.z, wv, a2);
            a3 = fmaf(xv.w, wv, a3);
        }
        red[g][0][c] = a0; red[g][1][c] = a1; red[g][2][c] = a2; red[g][3][c] = a3;
        __syncthreads();
        if (t < HD) {
            const float* bptr = (cb == 0) ? bq : (cb == 1) ? bk : (cb == 2) ? bv : bsk;
            const float bias = bptr[t];
            #pragma unroll
            for (int r = 0; r < PBM; ++r) {
                const float val = red[0][r][t] + red[1][r][t] + bias;
                const int row = r0 + r;
                if (cb == 3) {
                    skip[row * HD + t] = val;
                } else {
                    const int hnc = (t >> 4) * (NN * CH) + row * CH + (t & 15);
                    if (cb == 0)      q[hnc]  = val;
                    else if (cb == 1) kb[hnc] = f32_to_bf16(val);
                    else              vb[hnc] = f32_to_bf16(val);
                }
            }
        }
    }
}

// ---------------- K4: flash attention; 256-j chunks, cheap bf16 unpack ----------------
template<int REPS>
__global__ __launch_bounds__(256) void k_attn(
        const float* __restrict__ q, const unsigned short* __restrict__ kb,
        const unsigned short* __restrict__ vb, const float* __restrict__ skip,
        const unsigned short* __restrict__ wm, const float* __restrict__ We,
        float* __restrict__ x) {
    __shared__ unsigned short kS[2][CHK][CH];   // 16 KB
    __shared__ unsigned short vS[2][CHK][CH];   // 16 KB
    __shared__ float mrg[4][TT][20];            // per-wave partials {m,sum,aw,o[16]}
    const int i0 = blockIdx.x * TT;
    const int h  = blockIdx.y;
    const int t  = threadIdx.x;
    const int w  = t >> 6, l = t & 63;
    const int r  = l >> 3, js = l & 7;

    const unsigned short* kh = kb + h * (NN * CH);
    const unsigned short* vh = vb + h * (NN * CH);

    float qr[CH];
    {
        const float* qp = q + h * (NN * CH) + (i0 + r) * CH;
        const float4 q0 = *(const float4*)(qp + 0);
        const float4 q1 = *(const float4*)(qp + 4);
        const float4 q2 = *(const float4*)(qp + 8);
        const float4 q3 = *(const float4*)(qp + 12);
        qr[0]=q0.x*QSC; qr[1]=q0.y*QSC; qr[2]=q0.z*QSC; qr[3]=q0.w*QSC;
        qr[4]=q1.x*QSC; qr[5]=q1.y*QSC; qr[6]=q1.z*QSC; qr[7]=q1.w*QSC;
        qr[8]=q2.x*QSC; qr[9]=q2.y*QSC; qr[10]=q2.z*QSC; qr[11]=q2.w*QSC;
        qr[12]=q3.x*QSC; qr[13]=q3.y*QSC; qr[14]=q3.z*QSC; qr[15]=q3.w*QSC;
    }
    float qe = 0.f;
    #pragma unroll
    for (int c = 0; c < CH; ++c) qe = fmaf(qr[c], We[h * CH + c], qe);   // uniform -> scalar
    const unsigned short* wr = wm + (i0 + r) * NN;
    const int wb = w * 64;

    #pragma unroll 1
    for (int rep = 0; rep < REPS; ++rep) {
        float o[CH];
        #pragma unroll
        for (int c = 0; c < CH; ++c) o[c] = 0.f;
        float m = -1e30f, sum = 0.f, aw = 0.f;

        {   // prologue: stage chunk 0 (each thread: k row t AND v row t)
            const uint4* ks = (const uint4*)(kh + (size_t)t * CH);
            const uint4* vs = (const uint4*)(vh + (size_t)t * CH);
            uint4* kd = (uint4*)&kS[0][t][0];
            uint4* vd = (uint4*)&vS[0][t][0];
            kd[0] = ks[0]; kd[1] = ks[1];
            vd[0] = vs[0]; vd[1] = vs[1];
        }
        __syncthreads();

        int buf = 0;
        for (int ch = 0; ch < NN / CHK; ++ch) {
            if (ch + 1 < NN / CHK) {
                const size_t rg = (size_t)((ch + 1) * CHK + t) * CH;
                const uint4* ks = (const uint4*)(kh + rg);
                const uint4* vs = (const uint4*)(vh + rg);
                uint4* kd = (uint4*)&kS[buf ^ 1][t][0];
                uint4* vd = (uint4*)&vS[buf ^ 1][t][0];
                const uint4 a0 = ks[0], a1 = ks[1], b0 = vs[0], b1 = vs[1];
                kd[0] = a0; kd[1] = a1;
                vd[0] = b0; vd[1] = b1;
            }
            const int jb = ch * CHK;

            #pragma unroll
            for (int hf = 0; hf < 2; ++hf) {
                const int base = wb + hf * 32;
                float d[4];
                #pragma unroll
                for (int q2 = 0; q2 < 4; ++q2) {
                    const int jj = base + js + 8 * q2;
                    const uint4* kp = (const uint4*)&kS[buf][jj][0];
                    const uint4 A = kp[0], B = kp[1];
                    float acc = 0.f;
                    acc = fmaf(qr[0],  bflo(A.x), acc); acc = fmaf(qr[1],  rawf(A.x), acc);
                    acc = fmaf(qr[2],  bflo(A.y), acc); acc = fmaf(qr[3],  rawf(A.y), acc);
                    acc = fmaf(qr[4],  bflo(A.z), acc); acc = fmaf(qr[5],  rawf(A.z), acc);
                    acc = fmaf(qr[6],  bflo(A.w), acc); acc = fmaf(qr[7],  rawf(A.w), acc);
                    acc = fmaf(qr[8],  bflo(B.x), acc); acc = fmaf(qr[9],  rawf(B.x), acc);
                    acc = fmaf(qr[10], bflo(B.y), acc); acc = fmaf(qr[11], rawf(B.y), acc);
                    acc = fmaf(qr[12], bflo(B.z), acc); acc = fmaf(qr[13], rawf(B.z), acc);
                    acc = fmaf(qr[14], bflo(B.w), acc); acc = fmaf(qr[15], rawf(B.w), acc);
                    d[q2] = acc;
                }
                float s[4], wa[4];
                #pragma unroll
                for (int q2 = 0; q2 < 4; ++q2) {
                    const float wv = bf16_to_f32(wr[jb + base + js + 8 * q2]);   // sign = mask
                    wa[q2] = fabsf(wv);
                    s[q2] = (wv > 0.f) ? fmaf(qe, wa[q2], d[q2]) : -1e30f;
                }
                const float smax = fmaxf(fmaxf(s[0], s[1]), fmaxf(s[2], s[3]));
                if (smax > m) {
                    const float f = __builtin_amdgcn_exp2f(m - smax);
                    sum *= f; aw *= f;
                    #pragma unroll
                    for (int c = 0; c < CH; ++c) o[c] *= f;
                    m = smax;
                }
                float p[4];
                #pragma unroll
                for (int q2 = 0; q2 < 4; ++q2) {
                    p[q2] = __builtin_amdgcn_exp2f(s[q2] - m);   // masked: underflow -> 0
                    sum += p[q2];
                    aw = fmaf(p[q2], wa[q2], aw);
                }
                #pragma unroll
                for (int q2 = 0; q2 < 4; ++q2) {
                    const int jj = base + js + 8 * q2;
                    const float pq = p[q2];
                    const uint4* vp = (const uint4*)&vS[buf][jj][0];
                    const uint4 A = vp[0], B = vp[1];
                    o[0]  = fmaf(pq, bflo(A.x), o[0]);  o[1]  = fmaf(pq, rawf(A.x), o[1]);
                    o[2]  = fmaf(pq, bflo(A.y), o[2]);  o[3]  = fmaf(pq, rawf(A.y), o[3]);
                    o[4]  = fmaf(pq, bflo(A.z), o[4]);  o[5]  = fmaf(pq, rawf(A.z), o[5]);
                    o[6]  = fmaf(pq, bflo(A.w), o[6]);  o[7]  = fmaf(pq, rawf(A.w), o[7]);
                    o[8]  = fmaf(pq, bflo(B.x), o[8]);  o[9]  = fmaf(pq, rawf(B.x), o[9]);
                    o[10] = fmaf(pq, bflo(B.y), o[10]); o[11] = fmaf(pq, rawf(B.y), o[11]);
                    o[12] = fmaf(pq, bflo(B.z), o[12]); o[13] = fmaf(pq, rawf(B.z), o[13]);
                    o[14] = fmaf(pq, bflo(B.w), o[14]); o[15] = fmaf(pq, rawf(B.w), o[15]);
                }
            }
            __syncthreads();
            buf ^= 1;
        }

        #pragma unroll
        for (int off = 1; off < 8; off <<= 1) {
            const float mo = __shfl_xor(m, off);
            const float mn = fmaxf(m, mo);
            const float fs = __builtin_amdgcn_exp2f(m - mn);
            const float fo = __builtin_amdgcn_exp2f(mo - mn);
            sum = sum * fs + __shfl_xor(sum, off) * fo;
            aw  = aw  * fs + __shfl_xor(aw,  off) * fo;
            #pragma unroll
            for (int c = 0; c < CH; ++c)
                o[c] = o[c] * fs + __shfl_xor(o[c], off) * fo;
            m = mn;
        }
        if (js == 0) {
            float* mp = &mrg[w][r][0];
            mp[0] = m; mp[1] = sum; mp[2] = aw;
            #pragma unroll
            for (int c = 0; c < CH; ++c) mp[3 + c] = o[c];
        }
        __syncthreads();

        if (t < TT * CH) {
            const int r2 = t >> 4, c = t & 15;
            const float m0 = mrg[0][r2][0], m1 = mrg[1][r2][0], m2 = mrg[2][r2][0], m3 = mrg[3][r2][0];
            const float ms = fmaxf(fmaxf(m0, m1), fmaxf(m2, m3));
            const float f0 = __builtin_amdgcn_exp2f(m0 - ms);
            const float f1 = __builtin_amdgcn_exp2f(m1 - ms);
            const float f2 = __builtin_amdgcn_exp2f(m2 - ms);
            const float f3 = __builtin_amdgcn_exp2f(m3 - ms);
            const float sums = f0 * mrg[0][r2][1] + f1 * mrg[1][r2][1] + f2 * mrg[2][r2][1] + f3 * mrg[3][r2][1];
            const float aws  = f0 * mrg[0][r2][2] + f1 * mrg[1][r2][2] + f2 * mrg[2][r2][2] + f3 * mrg[3][r2][2];
            const float oc   = f0 * mrg[0][r2][3 + c] + f1 * mrg[1][r2][3 + c]
                             + f2 * mrg[2][r2][3 + c] + f3 * mrg[3][r2][3 + c];
            const float inv = (ms > -1e29f) ? 1.f / sums : 0.f;   // all-masked row -> 0
            const int idx = (i0 + r2) * HD + h * CH + c;
            x[idx] = x[idx] + skip[idx] + oc * inv + (aws * inv) * We[h * CH + c];
        }
        if (REPS > 1) __syncthreads();   // mrg reads done before next rep's dump
    }
}

// ---------------- launch: real chain (identical to r15) + counter-visible probes ----------------
extern "C" void kernel_launch(void* const* d_in, const int* in_sizes, int n_in,
                              void* d_out, int out_size, void* d_ws, size_t ws_size,
                              hipStream_t stream) {
    const float* ent = (const float*)d_in[2];
    const float* W1  = (const float*)d_in[3];
    const float* b1  = (const float*)d_in[4];
    const float* W2  = (const float*)d_in[5];
    const float* b2  = (const float*)d_in[6];
    const float* Wq  = (const float*)d_in[7];
    const float* bq  = (const float*)d_in[8];
    const float* Wk  = (const float*)d_in[9];
    const float* bk  = (const float*)d_in[10];
    const float* Wv  = (const float*)d_in[11];
    const float* bv  = (const float*)d_in[12];
    const float* We  = (const float*)d_in[13];
    const float* Ws  = (const float*)d_in[14];
    const float* bs  = (const float*)d_in[15];

    float* ws = (float*)d_ws;
    unsigned short* wm = (unsigned short*)d_ws;   // [1024][1024] bf16, sign = mask (2 MB)
    float* fb = ws + (NN * NN / 2);
    float* q  = fb;                               // [8][1024][16] f32 (reused as 'a' pre-layers)
    float* kf = q + NN * HD;                      // f32 scratch: 'b' for edge phase
    float* sk = kf + NN * HD;
    unsigned short* kb = (unsigned short*)(sk + NN * HD);   // [8][1024][16] bf16
    unsigned short* vb = kb + NN * HD;                      // [8][1024][16] bf16
    float* x  = (float*)d_out;                    // running entity state

    // ---- probe scratch (dead; never read by the real chain) ----
    float* P = ws + (2u << 20);                   // 8 MB offset
    float* q2   = P;
    float* sk2  = P + 131072;
    unsigned short* kb2 = (unsigned short*)(P + 262144);
    unsigned short* vb2 = (unsigned short*)(P + 327680);
    float* xscr = P + 393216;
    unsigned short* wm2 = (unsigned short*)(P + 524288);
    float* a2   = P + 1048576;
    float* b2s  = P + 1179648;
    float* xo2  = P + 1310720;

    // ======== real chain — byte-identical behavior to round 15 ========
    k_edge_ab<1><<<dim3(NN / ABM, 2), 256, 0, stream>>>(ent, W1, b1, q /*a*/, kf /*b*/, x);
    k_edge_w<1><<<dim3(32, 64), 256, 0, stream>>>(q, kf, W2, b2, wm);
    for (int l = 0; l < NLAYERS; ++l) {
        k_proj<1><<<dim3(NN / PBM, 4), 256, 0, stream>>>(x,
            Wq + l * HD * HD, bq + l * HD, Wk + l * HD * HD, bk + l * HD,
            Wv + l * HD * HD, bv + l * HD, Ws + l * HD * HD, bs + l * HD,
            q, kb, vb, sk);
        k_attn<1><<<dim3(NN / TT, NH), 256, 0, stream>>>(q, kb, vb, sk, wm, We + l * HD, x);
    }

    // ======== probes — same access patterns, REPS x duration -> visible in top-5 with counters ========
    // t_kernel = dur_probe / REPS. All outputs are dead scratch; inputs deterministic.
    k_attn<8><<<dim3(NN / TT, NH), 256, 0, stream>>>(q, kb, vb, sk, wm, We + 2 * HD, xscr);
    k_proj<24><<<dim3(NN / PBM, 4), 256, 0, stream>>>(x,
        Wq + 2 * HD * HD, bq + 2 * HD, Wk + 2 * HD * HD, bk + 2 * HD,
        Wv + 2 * HD * HD, bv + 2 * HD, Ws + 2 * HD * HD, bs + 2 * HD,
        q2, kb2, vb2, sk2);
    k_edge_w<16><<<dim3(32, 64), 256, 0, stream>>>(q, kf, W2, b2, wm2);
    k_edge_ab<24><<<dim3(NN / ABM, 2), 256, 0, stream>>>(ent, W1, b1, a2, b2s, xo2);
}

// Round 17
// 217.829 us; speedup vs baseline: 2.4978x; 2.4978x over previous
//
#include <hip/hip_runtime.h>
#include <math.h>

#define NN 1024     // entities
#define HD 128      // hidden dim
#define NH 8        // heads
#define CH 16       // dim per head
#define NLAYERS 3

#define TT 8        // target rows per attention block
#define ALP 130     // k_edge_w al row stride
#define PBM 4       // k_proj rows per block
#define ABM 2       // k_edge_ab rows per block
#define QSC 0.36067376022224085f   // 0.25 * log2(e)

__device__ __forceinline__ float bf16_to_f32(unsigned short u) {
    union { unsigned int i; float f; } x; x.i = ((unsigned int)u) << 16; return x.f;
}
__device__ __forceinline__ unsigned short f32_to_bf16(float f) {
    union { float f; unsigned int i; } x; x.f = f;
    const unsigned int r = x.i + 0x7FFFu + ((x.i >> 16) & 1u);   // RNE
    return (unsigned short)(r >> 16);
}
__device__ __forceinline__ float bflo(unsigned int u) {
    union { unsigned int i; float f; } x; x.i = u << 16; return x.f;
}
__device__ __forceinline__ float rawf(unsigned int u) {
    union { unsigned int i; float f; } x; x.i = u; return x.f;
}

// ---------------- K1: a = x@W1[:128], b = x@W1[128:] + b1; by==0 also copies x -> xout ----------------
__global__ __launch_bounds__(256) void k_edge_ab(
        const float* __restrict__ x, const float* __restrict__ W1,
        const float* __restrict__ b1, float* __restrict__ a, float* __restrict__ b,
        float* __restrict__ xout) {
    __shared__ float xt[HD][ABM];
    __shared__ float red[2][ABM][HD];
    const int r0 = blockIdx.x * ABM;
    const int cb = blockIdx.y;           // 0 -> a, 1 -> b
    const int t  = threadIdx.x;
    {
        const float xv = x[(r0 + (t >> 7)) * HD + (t & 127)];
        xt[t & 127][t >> 7] = xv;
        if (cb == 0) xout[(r0 + (t >> 7)) * HD + (t & 127)] = xv;   // fused x init
    }
    __syncthreads();
    const int c = t & 127, g = t >> 7;
    const float* wp = W1 + cb * HD * HD + g * 64 * HD + c;
    const float* xp = &xt[g * 64][0];
    float a0 = 0.f, a1 = 0.f;
    #pragma unroll 8
    for (int kk = 0; kk < 64; ++kk) {
        const float wv = wp[kk * HD];
        const float2 xv = *(const float2*)&xp[kk * ABM];
        a0 = fmaf(xv.x, wv, a0);
        a1 = fmaf(xv.y, wv, a1);
    }
    red[g][0][c] = a0; red[g][1][c] = a1;
    __syncthreads();
    if (t < HD) {
        float* dst = cb ? b : a;
        const float bias = cb ? b1[t] : 0.f;
        #pragma unroll
        for (int r = 0; r < ABM; ++r)
            dst[(r0 + r) * HD + t] = red[0][r][t] + red[1][r][t] + bias;
    }
}

// ---------------- K2: wm[t][s] = bf16( sign(mask) * sigmoid(logit[s][t]) ) ----------------
__global__ __launch_bounds__(256) void k_edge_w(
        const float* __restrict__ a, const float* __restrict__ bb,
        const float* __restrict__ W2, const float* __restrict__ b2,
        unsigned short* __restrict__ wm) {
    __shared__ float al[32][ALP];
    __shared__ float bl[16][HD];
    const int t = threadIdx.x;
    const int s0 = blockIdx.x * 32, t0 = blockIdx.y * 16;
    for (int ii = t; ii < 2048; ii += 256) {
        const int row = ii >> 6, col = (ii & 63) * 2;
        *(float2*)&al[row][col] = *(const float2*)&a[(s0 + row) * HD + col];
    }
    for (int ii = t; ii < 512; ii += 256) {
        const int row = ii >> 5, col = (ii & 31) * 4;
        *(float4*)&bl[row][col] = *(const float4*)&bb[(t0 + row) * HD + col];
    }
    __syncthreads();
    const int s = t & 31, tt = t >> 5;
    float acc0 = 0.f, acc1 = 0.f;
    #pragma unroll 2
    for (int h4 = 0; h4 < HD; h4 += 4) {
        const float4 w2 = *(const float4*)&W2[h4];
        const float2 avA = *(const float2*)&al[s][h4];
        const float2 avB = *(const float2*)&al[s][h4 + 2];
        const float4 b0v = *(const float4*)&bl[tt][h4];
        const float4 b1v = *(const float4*)&bl[tt + 8][h4];
        acc0 = fmaf(fmaxf(avA.x + b0v.x, 0.f), w2.x, acc0);
        acc0 = fmaf(fmaxf(avA.y + b0v.y, 0.f), w2.y, acc0);
        acc0 = fmaf(fmaxf(avB.x + b0v.z, 0.f), w2.z, acc0);
        acc0 = fmaf(fmaxf(avB.y + b0v.w, 0.f), w2.w, acc0);
        acc1 = fmaf(fmaxf(avA.x + b1v.x, 0.f), w2.x, acc1);
        acc1 = fmaf(fmaxf(avA.y + b1v.y, 0.f), w2.y, acc1);
        acc1 = fmaf(fmaxf(avB.x + b1v.z, 0.f), w2.z, acc1);
        acc1 = fmaf(fmaxf(avB.y + b1v.w, 0.f), w2.w, acc1);
    }
    const float bias = b2[0];
    const float l0 = acc0 + bias, l1 = acc1 + bias;
    const float w0 = 1.f / (1.f + __expf(-l0));
    const float w1 = 1.f / (1.f + __expf(-l1));
    wm[(t0 + tt    ) * NN + s0 + s] = f32_to_bf16((l0 > 0.f) ? w0 : -w0);   // sign encodes mask
    wm[(t0 + tt + 8) * NN + s0 + s] = f32_to_bf16((l1 > 0.f) ? w1 : -w1);
}

// ---------------- K3: projections q (f32), k,v (bf16) in [h][n][c] + skip (f32) ----------------
__global__ __launch_bounds__(256) void k_proj(
        const float* __restrict__ x,
        const float* __restrict__ Wq, const float* __restrict__ bq,
        const float* __restrict__ Wk, const float* __restrict__ bk,
        const float* __restrict__ Wv, const float* __restrict__ bv,
        const float* __restrict__ Wsk, const float* __restrict__ bsk,
        float* __restrict__ q, unsigned short* __restrict__ kb,
        unsigned short* __restrict__ vb, float* __restrict__ skip) {
    __shared__ float xt[HD][PBM];
    __shared__ float red[2][PBM][HD];
    const int r0 = blockIdx.x * PBM;
    const int cb = blockIdx.y;           // 0..3 -> q,k,v,skip
    const int t  = threadIdx.x;
    {
        const int r = t >> 6, c2 = (t & 63) * 2;
        const float2 xv = *(const float2*)&x[(r0 + r) * HD + c2];
        xt[c2][r] = xv.x; xt[c2 + 1][r] = xv.y;
    }
    __syncthreads();
    const int c = t & 127, g = t >> 7;
    const float* W = (cb == 0) ? Wq : (cb == 1) ? Wk : (cb == 2) ? Wv : Wsk;
    const float* wp = W + g * 64 * HD + c;
    const float* xp = &xt[g * 64][0];
    float a0 = 0.f, a1 = 0.f, a2 = 0.f, a3 = 0.f;
    #pragma unroll 8
    for (int kk = 0; kk < 64; ++kk) {
        const float wv = wp[kk * HD];
        const float4 xv = *(const float4*)&xp[kk * PBM];
        a0 = fmaf(xv.x, wv, a0);
        a1 = fmaf(xv.y, wv, a1);
        a2 = fmaf(xv.z, wv, a2);
        a3 = fmaf(xv.w, wv, a3);
    }
    red[g][0][c] = a0; red[g][1][c] = a1; red[g][2][c] = a2; red[g][3][c] = a3;
    __syncthreads();
    if (t < HD) {
        const float* bptr = (cb == 0) ? bq : (cb == 1) ? bk : (cb == 2) ? bv : bsk;
        const float bias = bptr[t];
        #pragma unroll
        for (int r = 0; r < PBM; ++r) {
            const float val = red[0][r][t] + red[1][r][t] + bias;
            const int row = r0 + r;
            if (cb == 3) {
                skip[row * HD + t] = val;
            } else {
                const int hnc = (t >> 4) * (NN * CH) + row * CH + (t & 15);
                if (cb == 0)      q[hnc]  = val;
                else if (cb == 1) kb[hnc] = f32_to_bf16(val);
                else              vb[hnc] = f32_to_bf16(val);
            }
        }
    }
}

// ---------------- K4: flash attention, NO LDS STAGING (k/v L1/L2-direct), no main-loop barriers ----------------
// grid (NN/TT, NH). 4 waves; lane = (row-group r = l>>3, js = l&7); wave w owns j in [w*64, w*64+64) mod 256.
// Lane's 4 j's are CONTIGUOUS (js*4 + q2) -> wm loads as one ushort4.
__global__ __launch_bounds__(256) void k_attn(
        const float* __restrict__ q, const unsigned short* __restrict__ kb,
        const unsigned short* __restrict__ vb, const float* __restrict__ skip,
        const unsigned short* __restrict__ wm, const float* __restrict__ We,
        float* __restrict__ x) {
    __shared__ float mrg[4][TT][20];     // 2.5 KB: per-wave partials {m,sum,aw,o[16]}
    const int i0 = blockIdx.x * TT;
    const int h  = blockIdx.y;
    const int t  = threadIdx.x;
    const int w  = t >> 6, l = t & 63;
    const int r  = l >> 3, js = l & 7;

    const unsigned short* kh = kb + h * (NN * CH);
    const unsigned short* vh = vb + h * (NN * CH);

    // q row (broadcast within 8-lane group), scaled into exp2 domain
    float qr[CH];
    {
        const float* qp = q + h * (NN * CH) + (i0 + r) * CH;
        const float4 q0 = *(const float4*)(qp + 0);
        const float4 q1 = *(const float4*)(qp + 4);
        const float4 q2 = *(const float4*)(qp + 8);
        const float4 q3 = *(const float4*)(qp + 12);
        qr[0]=q0.x*QSC; qr[1]=q0.y*QSC; qr[2]=q0.z*QSC; qr[3]=q0.w*QSC;
        qr[4]=q1.x*QSC; qr[5]=q1.y*QSC; qr[6]=q1.z*QSC; qr[7]=q1.w*QSC;
        qr[8]=q2.x*QSC; qr[9]=q2.y*QSC; qr[10]=q2.z*QSC; qr[11]=q2.w*QSC;
        qr[12]=q3.x*QSC; qr[13]=q3.y*QSC; qr[14]=q3.z*QSC; qr[15]=q3.w*QSC;
    }
    float qe = 0.f;
    #pragma unroll
    for (int c = 0; c < CH; ++c) qe = fmaf(qr[c], We[h * CH + c], qe);   // uniform -> scalar
    const unsigned short* wr = wm + (i0 + r) * NN;

    float o[CH];
    #pragma unroll
    for (int c = 0; c < CH; ++c) o[c] = 0.f;
    float m = -1e30f, sum = 0.f, aw = 0.f;

    // main loop: 8 passes of 32 j per wave; j = pass-base + js*4 + q2 (contiguous per lane)
    #pragma unroll 1
    for (int ps = 0; ps < 8; ++ps) {
        const int base = (ps >> 1) * 256 + w * 64 + (ps & 1) * 32;   // wave's 32-j window
        const int j0 = base + js * 4;                                 // lane's first j

        // k rows for q2=0..3 (prefetched together; 8 x uint4 live)
        const uint4* kp = (const uint4*)(kh + (size_t)j0 * CH);
        const uint4 K0A = kp[0], K0B = kp[1], K1A = kp[2], K1B = kp[3];
        const uint4 K2A = kp[4], K2B = kp[5], K3A = kp[6], K3B = kp[7];
        const ushort4 w4 = *(const ushort4*)&wr[j0];                  // 4 contiguous edge weights

        float d[4];
        {
            float acc;
            #define QKDOT(A, B) ( \
                acc = 0.f, \
                acc = fmaf(qr[0],  bflo(A.x), acc), acc = fmaf(qr[1],  rawf(A.x), acc), \
                acc = fmaf(qr[2],  bflo(A.y), acc), acc = fmaf(qr[3],  rawf(A.y), acc), \
                acc = fmaf(qr[4],  bflo(A.z), acc), acc = fmaf(qr[5],  rawf(A.z), acc), \
                acc = fmaf(qr[6],  bflo(A.w), acc), acc = fmaf(qr[7],  rawf(A.w), acc), \
                acc = fmaf(qr[8],  bflo(B.x), acc), acc = fmaf(qr[9],  rawf(B.x), acc), \
                acc = fmaf(qr[10], bflo(B.y), acc), acc = fmaf(qr[11], rawf(B.y), acc), \
                acc = fmaf(qr[12], bflo(B.z), acc), acc = fmaf(qr[13], rawf(B.z), acc), \
                acc = fmaf(qr[14], bflo(B.w), acc), acc = fmaf(qr[15], rawf(B.w), acc), acc )
            d[0] = QKDOT(K0A, K0B);
            d[1] = QKDOT(K1A, K1B);
            d[2] = QKDOT(K2A, K2B);
            d[3] = QKDOT(K3A, K3B);
            #undef QKDOT
        }
        // v rows (issued before softmax math so latency hides under it)
        const uint4* vp = (const uint4*)(vh + (size_t)j0 * CH);
        const uint4 V0A = vp[0], V0B = vp[1], V1A = vp[2], V1B = vp[3];
        const uint4 V2A = vp[4], V2B = vp[5], V3A = vp[6], V3B = vp[7];

        // edge weight + mask -> s (exp2 domain); masked -> -1e30 (underflows to p=0)
        float s[4], wa[4];
        const unsigned short wu[4] = {w4.x, w4.y, w4.z, w4.w};
        #pragma unroll
        for (int q2 = 0; q2 < 4; ++q2) {
            const float wv = bf16_to_f32(wu[q2]);   // sign = mask
            wa[q2] = fabsf(wv);
            s[q2] = (wv > 0.f) ? fmaf(qe, wa[q2], d[q2]) : -1e30f;
        }
        // defer-max: rescale only when the running max grows
        const float smax = fmaxf(fmaxf(s[0], s[1]), fmaxf(s[2], s[3]));
        if (smax > m) {
            const float f = __builtin_amdgcn_exp2f(m - smax);
            sum *= f; aw *= f;
            #pragma unroll
            for (int c = 0; c < CH; ++c) o[c] *= f;
            m = smax;
        }
        float p[4];
        #pragma unroll
        for (int q2 = 0; q2 < 4; ++q2) {
            p[q2] = __builtin_amdgcn_exp2f(s[q2] - m);   // masked: underflow -> 0
            sum += p[q2];
            aw = fmaf(p[q2], wa[q2], aw);
        }
        // PV
        #define PVACC(pq, A, B) \
            o[0]  = fmaf(pq, bflo(A.x), o[0]);  o[1]  = fmaf(pq, rawf(A.x), o[1]);  \
            o[2]  = fmaf(pq, bflo(A.y), o[2]);  o[3]  = fmaf(pq, rawf(A.y), o[3]);  \
            o[4]  = fmaf(pq, bflo(A.z), o[4]);  o[5]  = fmaf(pq, rawf(A.z), o[5]);  \
            o[6]  = fmaf(pq, bflo(A.w), o[6]);  o[7]  = fmaf(pq, rawf(A.w), o[7]);  \
            o[8]  = fmaf(pq, bflo(B.x), o[8]);  o[9]  = fmaf(pq, rawf(B.x), o[9]);  \
            o[10] = fmaf(pq, bflo(B.y), o[10]); o[11] = fmaf(pq, rawf(B.y), o[11]); \
            o[12] = fmaf(pq, bflo(B.z), o[12]); o[13] = fmaf(pq, rawf(B.z), o[13]); \
            o[14] = fmaf(pq, bflo(B.w), o[14]); o[15] = fmaf(pq, rawf(B.w), o[15]);
        PVACC(p[0], V0A, V0B)
        PVACC(p[1], V1A, V1B)
        PVACC(p[2], V2A, V2B)
        PVACC(p[3], V3A, V3B)
        #undef PVACC
    }

    // intra-wave merge over the 8 js-lanes (rescaled combine)
    #pragma unroll
    for (int off = 1; off < 8; off <<= 1) {
        const float mo = __shfl_xor(m, off);
        const float mn = fmaxf(m, mo);
        const float fs = __builtin_amdgcn_exp2f(m - mn);
        const float fo = __builtin_amdgcn_exp2f(mo - mn);
        sum = sum * fs + __shfl_xor(sum, off) * fo;
        aw  = aw  * fs + __shfl_xor(aw,  off) * fo;
        #pragma unroll
        for (int c = 0; c < CH; ++c)
            o[c] = o[c] * fs + __shfl_xor(o[c], off) * fo;
        m = mn;
    }
    if (js == 0) {       // dump wave-partial for (w, r)
        float* mp = &mrg[w][r][0];
        mp[0] = m; mp[1] = sum; mp[2] = aw;
        #pragma unroll
        for (int c = 0; c < CH; ++c) mp[3 + c] = o[c];
    }
    __syncthreads();

    // final combine: thread (r2, c) merges the 4 wave-partials and writes x
    if (t < TT * CH) {
        const int r2 = t >> 4, c = t & 15;
        const float m0 = mrg[0][r2][0], m1 = mrg[1][r2][0], m2 = mrg[2][r2][0], m3 = mrg[3][r2][0];
        const float ms = fmaxf(fmaxf(m0, m1), fmaxf(m2, m3));
        const float f0 = __builtin_amdgcn_exp2f(m0 - ms);
        const float f1 = __builtin_amdgcn_exp2f(m1 - ms);
        const float f2 = __builtin_amdgcn_exp2f(m2 - ms);
        const float f3 = __builtin_amdgcn_exp2f(m3 - ms);
        const float sums = f0 * mrg[0][r2][1] + f1 * mrg[1][r2][1] + f2 * mrg[2][r2][1] + f3 * mrg[3][r2][1];
        const float aws  = f0 * mrg[0][r2][2] + f1 * mrg[1][r2][2] + f2 * mrg[2][r2][2] + f3 * mrg[3][r2][2];
        const float oc   = f0 * mrg[0][r2][3 + c] + f1 * mrg[1][r2][3 + c]
                         + f2 * mrg[2][r2][3 + c] + f3 * mrg[3][r2][3 + c];
        const float inv = (ms > -1e29f) ? 1.f / sums : 0.f;   // all-masked row -> 0
        const int idx = (i0 + r2) * HD + h * CH + c;
        x[idx] = x[idx] + skip[idx] + oc * inv + (aws * inv) * We[h * CH + c];
    }
}

// ---------------- launch ----------------
extern "C" void kernel_launch(void* const* d_in, const int* in_sizes, int n_in,
                              void* d_out, int out_size, void* d_ws, size_t ws_size,
                              hipStream_t stream) {
    const float* ent = (const float*)d_in[2];
    const float* W1  = (const float*)d_in[3];
    const float* b1  = (const float*)d_in[4];
    const float* W2  = (const float*)d_in[5];
    const float* b2  = (const float*)d_in[6];
    const float* Wq  = (const float*)d_in[7];
    const float* bq  = (const float*)d_in[8];
    const float* Wk  = (const float*)d_in[9];
    const float* bk  = (const float*)d_in[10];
    const float* Wv  = (const float*)d_in[11];
    const float* bv  = (const float*)d_in[12];
    const float* We  = (const float*)d_in[13];
    const float* Ws  = (const float*)d_in[14];
    const float* bs  = (const float*)d_in[15];

    unsigned short* wm = (unsigned short*)d_ws;   // [1024][1024] bf16, sign = mask (2 MB)
    float* fb = (float*)d_ws + (NN * NN / 2);     // float area after wm
    float* q  = fb;                               // [8][1024][16] f32 (reused as 'a' pre-layers)
    float* kf = q + NN * HD;                      // f32 scratch: 'b' for edge phase
    float* sk = kf + NN * HD;
    unsigned short* kb = (unsigned short*)(sk + NN * HD);   // [8][1024][16] bf16
    unsigned short* vb = kb + NN * HD;                      // [8][1024][16] bf16
    float* x  = (float*)d_out;                    // running entity state

    k_edge_ab<<<dim3(NN / ABM, 2), 256, 0, stream>>>(ent, W1, b1, q /*a*/, kf /*b*/, x);
    k_edge_w<<<dim3(32, 64), 256, 0, stream>>>(q, kf, W2, b2, wm);

    for (int l = 0; l < NLAYERS; ++l) {
        k_proj<<<dim3(NN / PBM, 4), 256, 0, stream>>>(x,
            Wq + l * HD * HD, bq + l * HD, Wk + l * HD * HD, bk + l * HD,
            Wv + l * HD * HD, bv + l * HD, Ws + l * HD * HD, bs + l * HD,
            q, kb, vb, sk);
        k_attn<<<dim3(NN / TT, NH), 256, 0, stream>>>(q, kb, vb, sk, wm, We + l * HD, x);
    }
}

// Round 18
// 82.290 us; speedup vs baseline: 6.6120x; 2.6471x over previous
//
#include <hip/hip_runtime.h>
#include <math.h>

#define NN 1024     // entities
#define HD 128      // hidden dim
#define NH 8        // heads
#define CH 16       // dim per head
#define NLAYERS 3

#define ALP 130     // k_edge_w al row stride
#define PBM 4       // k_proj rows per block
#define ABM 2       // k_edge_ab rows per block
#define QSC 0.36067376022224085f   // 0.25 * log2(e)

typedef __attribute__((ext_vector_type(8))) short short8;   // 8 bf16 (4 VGPR) MFMA operand
typedef __attribute__((ext_vector_type(4))) float f32x4;    // MFMA accumulator

union FRG { uint4 u; short8 s; };

__device__ __forceinline__ float bf16_to_f32(unsigned short u) {
    union { unsigned int i; float f; } x; x.i = ((unsigned int)u) << 16; return x.f;
}
__device__ __forceinline__ unsigned short f32_to_bf16(float f) {
    union { float f; unsigned int i; } x; x.f = f;
    const unsigned int r = x.i + 0x7FFFu + ((x.i >> 16) & 1u);   // RNE
    return (unsigned short)(r >> 16);
}
__device__ __forceinline__ unsigned int fbits(float f) {
    union { float f; unsigned int i; } x; x.f = f; return x.i;
}

// ---------------- K1: a = x@W1[:128], b = x@W1[128:] + b1; by==0 also copies x -> xout ----------------
__global__ __launch_bounds__(256) void k_edge_ab(
        const float* __restrict__ x, const float* __restrict__ W1,
        const float* __restrict__ b1, float* __restrict__ a, float* __restrict__ b,
        float* __restrict__ xout) {
    __shared__ float xt[HD][ABM];
    __shared__ float red[2][ABM][HD];
    const int r0 = blockIdx.x * ABM;
    const int cb = blockIdx.y;           // 0 -> a, 1 -> b
    const int t  = threadIdx.x;
    {
        const float xv = x[(r0 + (t >> 7)) * HD + (t & 127)];
        xt[t & 127][t >> 7] = xv;
        if (cb == 0) xout[(r0 + (t >> 7)) * HD + (t & 127)] = xv;   // fused x init
    }
    __syncthreads();
    const int c = t & 127, g = t >> 7;
    const float* wp = W1 + cb * HD * HD + g * 64 * HD + c;
    const float* xp = &xt[g * 64][0];
    float a0 = 0.f, a1 = 0.f;
    #pragma unroll 8
    for (int kk = 0; kk < 64; ++kk) {
        const float wv = wp[kk * HD];
        const float2 xv = *(const float2*)&xp[kk * ABM];
        a0 = fmaf(xv.x, wv, a0);
        a1 = fmaf(xv.y, wv, a1);
    }
    red[g][0][c] = a0; red[g][1][c] = a1;
    __syncthreads();
    if (t < HD) {
        float* dst = cb ? b : a;
        const float bias = cb ? b1[t] : 0.f;
        #pragma unroll
        for (int r = 0; r < ABM; ++r)
            dst[(r0 + r) * HD + t] = red[0][r][t] + red[1][r][t] + bias;
    }
}

// ---------------- K2: wm[t][s] = bf16( sign(mask) * sigmoid(logit[s][t]) ) ----------------
__global__ __launch_bounds__(256) void k_edge_w(
        const float* __restrict__ a, const float* __restrict__ bb,
        const float* __restrict__ W2, const float* __restrict__ b2,
        unsigned short* __restrict__ wm) {
    __shared__ float al[32][ALP];
    __shared__ float bl[16][HD];
    const int t = threadIdx.x;
    const int s0 = blockIdx.x * 32, t0 = blockIdx.y * 16;
    for (int ii = t; ii < 2048; ii += 256) {
        const int row = ii >> 6, col = (ii & 63) * 2;
        *(float2*)&al[row][col] = *(const float2*)&a[(s0 + row) * HD + col];
    }
    for (int ii = t; ii < 512; ii += 256) {
        const int row = ii >> 5, col = (ii & 31) * 4;
        *(float4*)&bl[row][col] = *(const float4*)&bb[(t0 + row) * HD + col];
    }
    __syncthreads();
    const int s = t & 31, tt = t >> 5;
    float acc0 = 0.f, acc1 = 0.f;
    #pragma unroll 2
    for (int h4 = 0; h4 < HD; h4 += 4) {
        const float4 w2 = *(const float4*)&W2[h4];
        const float2 avA = *(const float2*)&al[s][h4];
        const float2 avB = *(const float2*)&al[s][h4 + 2];
        const float4 b0v = *(const float4*)&bl[tt][h4];
        const float4 b1v = *(const float4*)&bl[tt + 8][h4];
        acc0 = fmaf(fmaxf(avA.x + b0v.x, 0.f), w2.x, acc0);
        acc0 = fmaf(fmaxf(avA.y + b0v.y, 0.f), w2.y, acc0);
        acc0 = fmaf(fmaxf(avB.x + b0v.z, 0.f), w2.z, acc0);
        acc0 = fmaf(fmaxf(avB.y + b0v.w, 0.f), w2.w, acc0);
        acc1 = fmaf(fmaxf(avA.x + b1v.x, 0.f), w2.x, acc1);
        acc1 = fmaf(fmaxf(avA.y + b1v.y, 0.f), w2.y, acc1);
        acc1 = fmaf(fmaxf(avB.x + b1v.z, 0.f), w2.z, acc1);
        acc1 = fmaf(fmaxf(avB.y + b1v.w, 0.f), w2.w, acc1);
    }
    const float bias = b2[0];
    const float l0 = acc0 + bias, l1 = acc1 + bias;
    const float w0 = 1.f / (1.f + __expf(-l0));
    const float w1 = 1.f / (1.f + __expf(-l1));
    wm[(t0 + tt    ) * NN + s0 + s] = f32_to_bf16((l0 > 0.f) ? w0 : -w0);   // sign encodes mask
    wm[(t0 + tt + 8) * NN + s0 + s] = f32_to_bf16((l1 > 0.f) ? w1 : -w1);
}

// ---------------- K3: projections qb,kb (bf16 [h][n][c]), vT (bf16 [h][c][n]) + skip (f32) ----------------
__global__ __launch_bounds__(256) void k_proj(
        const float* __restrict__ x,
        const float* __restrict__ Wq, const float* __restrict__ bq,
        const float* __restrict__ Wk, const float* __restrict__ bk,
        const float* __restrict__ Wv, const float* __restrict__ bv,
        const float* __restrict__ Wsk, const float* __restrict__ bsk,
        unsigned short* __restrict__ qb, unsigned short* __restrict__ kb,
        unsigned short* __restrict__ vT, float* __restrict__ skip) {
    __shared__ float xt[HD][PBM];
    __shared__ float red[2][PBM][HD];
    const int r0 = blockIdx.x * PBM;
    const int cb = blockIdx.y;           // 0..3 -> q,k,v,skip
    const int t  = threadIdx.x;
    {
        const int r = t >> 6, c2 = (t & 63) * 2;
        const float2 xv = *(const float2*)&x[(r0 + r) * HD + c2];
        xt[c2][r] = xv.x; xt[c2 + 1][r] = xv.y;
    }
    __syncthreads();
    const int c = t & 127, g = t >> 7;
    const float* W = (cb == 0) ? Wq : (cb == 1) ? Wk : (cb == 2) ? Wv : Wsk;
    const float* wp = W + g * 64 * HD + c;
    const float* xp = &xt[g * 64][0];
    float a0 = 0.f, a1 = 0.f, a2 = 0.f, a3 = 0.f;
    #pragma unroll 8
    for (int kk = 0; kk < 64; ++kk) {
        const float wv = wp[kk * HD];
        const float4 xv = *(const float4*)&xp[kk * PBM];
        a0 = fmaf(xv.x, wv, a0);
        a1 = fmaf(xv.y, wv, a1);
        a2 = fmaf(xv.z, wv, a2);
        a3 = fmaf(xv.w, wv, a3);
    }
    red[g][0][c] = a0; red[g][1][c] = a1; red[g][2][c] = a2; red[g][3][c] = a3;
    __syncthreads();
    if (t < HD) {
        const float* bptr = (cb == 0) ? bq : (cb == 1) ? bk : (cb == 2) ? bv : bsk;
        const float bias = bptr[t];
        const int h = t >> 4, ch = t & 15;
        #pragma unroll
        for (int r = 0; r < PBM; ++r) {
            const float val = red[0][r][t] + red[1][r][t] + bias;
            const int row = r0 + r;
            if (cb == 3) {
                skip[row * HD + t] = val;
            } else if (cb == 0) {
                qb[(h * NN + row) * CH + ch] = f32_to_bf16(val);
            } else if (cb == 1) {
                kb[(h * NN + row) * CH + ch] = f32_to_bf16(val);
            } else {
                vT[(h * CH + ch) * NN + row] = f32_to_bf16(val);   // transposed for PV B-frag
            }
        }
    }
}

// ---------------- K4: MFMA flash attention ----------------
// grid (NN/16, NH); 4 waves x 256-j strips. Per 16-j tile: S^T = mfma(K_rows, Q)
// -> lane holds s at (i = lane&15, j = 4*(lane>>4)+reg). Two-pass softmax; PV via
// mfma(P, V) with P redistributed by shfl into A-layout and V read from vT.
__global__ __launch_bounds__(256) void k_attn(
        const unsigned short* __restrict__ qb, const unsigned short* __restrict__ kb,
        const unsigned short* __restrict__ vT, const float* __restrict__ skip,
        const unsigned short* __restrict__ wm, const float* __restrict__ We,
        float* __restrict__ x) {
    __shared__ float mrg[4][16][20];     // per-wave partials {m,sum,aw,o[16]}
    const int i0 = blockIdx.x * 16;
    const int h  = blockIdx.y;
    const int t  = threadIdx.x;
    const int w  = t >> 6, l = t & 63;
    const int li = l & 15, G = l >> 4;

    // Q B-frag (persistent): B[k][i]: col=lane&15=i, k=8G+e (k>=16 -> zero)
    FRG qf;
    if (G < 2) qf.u = *(const uint4*)(qb + ((size_t)h * NN + i0 + li) * CH + 8 * G);
    else       qf.u = make_uint4(0, 0, 0, 0);

    // qe[i] = dot(q[i], We[h]) * QSC   (i = li)
    float qe = 0.f;
    {
        const uint4 qa = *(const uint4*)(qb + ((size_t)h * NN + i0 + li) * CH);
        const uint4 qb2 = *(const uint4*)(qb + ((size_t)h * NN + i0 + li) * CH + 8);
        const unsigned int qd[8] = {qa.x, qa.y, qa.z, qa.w, qb2.x, qb2.y, qb2.z, qb2.w};
        #pragma unroll
        for (int d2 = 0; d2 < 8; ++d2) {
            qe = fmaf(bf16_to_f32((unsigned short)(qd[d2] & 0xffff)), We[h * CH + 2 * d2], qe);
            qe = fmaf(bf16_to_f32((unsigned short)(qd[d2] >> 16)),    We[h * CH + 2 * d2 + 1], qe);
        }
        qe *= QSC;
    }
    const unsigned short* wrow = wm + (size_t)(i0 + li) * NN;
    const int j0s = w * 256;             // this wave's j strip

    // ---- pass 1: 16 QK^T tiles; stash logits; track row max (per-lane: fixed i) ----
    float m = -1e30f;
    float sst[16][4];
    #pragma unroll
    for (int tt = 0; tt < 16; ++tt) {
        const int j0 = j0s + tt * 16;
        FRG kf;
        if (G < 2) kf.u = *(const uint4*)(kb + ((size_t)h * NN + j0 + li) * CH + 8 * G);
        else       kf.u = make_uint4(0, 0, 0, 0);
        f32x4 d = __builtin_amdgcn_mfma_f32_16x16x32_bf16(kf.s, qf.s, (f32x4){0.f, 0.f, 0.f, 0.f}, 0, 0, 0);
        const uint2 wmu = *(const uint2*)(wrow + j0 + 4 * G);
        const unsigned short wu[4] = {(unsigned short)(wmu.x & 0xffff), (unsigned short)(wmu.x >> 16),
                                      (unsigned short)(wmu.y & 0xffff), (unsigned short)(wmu.y >> 16)};
        #pragma unroll
        for (int rg = 0; rg < 4; ++rg) {
            const float wv = bf16_to_f32(wu[rg]);               // sign = mask; wv>0 -> wa = wv
            const float sv = (wv > 0.f) ? fmaf(qe, wv, d[rg] * QSC) : -1e30f;
            sst[tt][rg] = sv;
            m = fmaxf(m, sv);
        }
    }
    m = fmaxf(m, __shfl_xor(m, 16));
    m = fmaxf(m, __shfl_xor(m, 32));     // final row max for i = li over this strip

    // ---- pass 2: p = exp2(s-m); sum/aw; P->bf16 -> shfl to A-layout -> PV mfma ----
    f32x4 oc = {0.f, 0.f, 0.f, 0.f};
    float sum = 0.f, aw = 0.f;
    const int srcA = (G & 1) * 32 + li;
    const int srcB = srcA + 16;
    #pragma unroll
    for (int cc = 0; cc < 8; ++cc) {
        unsigned int pk[4];              // {tile0:j01, tile0:j23, tile1:j01, tile1:j23}
        #pragma unroll
        for (int hh = 0; hh < 2; ++hh) {
            const int tt = 2 * cc + hh;
            const uint2 wmu = *(const uint2*)(wrow + j0s + tt * 16 + 4 * G);
            const unsigned short wu[4] = {(unsigned short)(wmu.x & 0xffff), (unsigned short)(wmu.x >> 16),
                                          (unsigned short)(wmu.y & 0xffff), (unsigned short)(wmu.y >> 16)};
            float p[4];
            #pragma unroll
            for (int rg = 0; rg < 4; ++rg) {
                p[rg] = __builtin_amdgcn_exp2f(sst[tt][rg] - m);   // masked underflows to 0
                sum += p[rg];
                aw = fmaf(p[rg], fabsf(bf16_to_f32(wu[rg])), aw);
            }
            pk[2 * hh]     = (fbits(p[0]) >> 16) | (fbits(p[1]) & 0xffff0000u);   // truncation pack
            pk[2 * hh + 1] = (fbits(p[2]) >> 16) | (fbits(p[3]) & 0xffff0000u);
        }
        // gather A-frag: lane needs p at (i=li, j32 = 8G+e)
        const unsigned int a0 = (unsigned int)__shfl((int)pk[0], srcA);
        const unsigned int a1 = (unsigned int)__shfl((int)pk[1], srcA);
        const unsigned int a2 = (unsigned int)__shfl((int)pk[0], srcB);
        const unsigned int a3 = (unsigned int)__shfl((int)pk[1], srcB);
        const unsigned int b0 = (unsigned int)__shfl((int)pk[2], srcA);
        const unsigned int b1 = (unsigned int)__shfl((int)pk[3], srcA);
        const unsigned int b2 = (unsigned int)__shfl((int)pk[2], srcB);
        const unsigned int b3 = (unsigned int)__shfl((int)pk[3], srcB);
        FRG pf;
        pf.u.x = (G >= 2) ? b0 : a0;
        pf.u.y = (G >= 2) ? b1 : a1;
        pf.u.z = (G >= 2) ? b2 : a2;
        pf.u.w = (G >= 2) ? b3 : a3;
        FRG vf;                          // B[k=j][c]: col=li=c, k=8G+e -> uint4 from vT
        vf.u = *(const uint4*)(vT + ((size_t)h * CH + li) * NN + j0s + cc * 32 + 8 * G);
        oc = __builtin_amdgcn_mfma_f32_16x16x32_bf16(pf.s, vf.s, oc, 0, 0, 0);
    }
    sum += __shfl_xor(sum, 16); sum += __shfl_xor(sum, 32);
    aw  += __shfl_xor(aw, 16);  aw  += __shfl_xor(aw, 32);

    // dump wave partials: m/sum/aw keyed by i=li (lanes G==0); out keyed by i=4G+rg, c=li
    if (l < 16) { mrg[w][l][0] = m; mrg[w][l][1] = sum; mrg[w][l][2] = aw; }
    #pragma unroll
    for (int rg = 0; rg < 4; ++rg) mrg[w][4 * G + rg][3 + li] = oc[rg];
    __syncthreads();

    // final combine: thread (r2, c) merges the 4 wave-partials and writes x
    {
        const int r2 = t >> 4, c = t & 15;
        const float m0 = mrg[0][r2][0], m1 = mrg[1][r2][0], m2 = mrg[2][r2][0], m3 = mrg[3][r2][0];
        const float ms = fmaxf(fmaxf(m0, m1), fmaxf(m2, m3));
        const float f0 = __builtin_amdgcn_exp2f(m0 - ms);
        const float f1 = __builtin_amdgcn_exp2f(m1 - ms);
        const float f2 = __builtin_amdgcn_exp2f(m2 - ms);
        const float f3 = __builtin_amdgcn_exp2f(m3 - ms);
        const float sums = f0 * mrg[0][r2][1] + f1 * mrg[1][r2][1] + f2 * mrg[2][r2][1] + f3 * mrg[3][r2][1];
        const float aws  = f0 * mrg[0][r2][2] + f1 * mrg[1][r2][2] + f2 * mrg[2][r2][2] + f3 * mrg[3][r2][2];
        const float ocm  = f0 * mrg[0][r2][3 + c] + f1 * mrg[1][r2][3 + c]
                         + f2 * mrg[2][r2][3 + c] + f3 * mrg[3][r2][3 + c];
        const float inv = (ms > -1e29f) ? 1.f / sums : 0.f;   // all-masked row -> 0
        const int idx = (i0 + r2) * HD + h * CH + c;
        x[idx] = x[idx] + skip[idx] + ocm * inv + (aws * inv) * We[h * CH + c];
    }
}

// ---------------- launch ----------------
extern "C" void kernel_launch(void* const* d_in, const int* in_sizes, int n_in,
                              void* d_out, int out_size, void* d_ws, size_t ws_size,
                              hipStream_t stream) {
    const float* ent = (const float*)d_in[2];
    const float* W1  = (const float*)d_in[3];
    const float* b1  = (const float*)d_in[4];
    const float* W2  = (const float*)d_in[5];
    const float* b2  = (const float*)d_in[6];
    const float* Wq  = (const float*)d_in[7];
    const float* bq  = (const float*)d_in[8];
    const float* Wk  = (const float*)d_in[9];
    const float* bk  = (const float*)d_in[10];
    const float* Wv  = (const float*)d_in[11];
    const float* bv  = (const float*)d_in[12];
    const float* We  = (const float*)d_in[13];
    const float* Ws  = (const float*)d_in[14];
    const float* bs  = (const float*)d_in[15];

    unsigned short* wm = (unsigned short*)d_ws;   // [1024][1024] bf16, sign = mask (2 MB)
    float* a  = (float*)(wm + (size_t)NN * NN);   // f32 scratch for edge phase
    float* bf = a + NN * HD;
    float* sk = bf + NN * HD;
    unsigned short* qb = (unsigned short*)(sk + NN * HD);   // [8][1024][16] bf16
    unsigned short* kb = qb + NN * HD;                      // [8][1024][16] bf16
    unsigned short* vT = kb + NN * HD;                      // [8][16][1024] bf16 (transposed)
    float* x  = (float*)d_out;                    // running entity state

    k_edge_ab<<<dim3(NN / ABM, 2), 256, 0, stream>>>(ent, W1, b1, a, bf, x);
    k_edge_w<<<dim3(32, 64), 256, 0, stream>>>(a, bf, W2, b2, wm);

    for (int l = 0; l < NLAYERS; ++l) {
        k_proj<<<dim3(NN / PBM, 4), 256, 0, stream>>>(x,
            Wq + l * HD * HD, bq + l * HD, Wk + l * HD * HD, bk + l * HD,
            Wv + l * HD * HD, bv + l * HD, Ws + l * HD * HD, bs + l * HD,
            qb, kb, vT, sk);
        k_attn<<<dim3(NN / 16, NH), 256, 0, stream>>>(qb, kb, vT, sk, wm, We + l * HD, x);
    }
}

// Round 19
// 78.387 us; speedup vs baseline: 6.9412x; 1.0498x over previous
//
#include <hip/hip_runtime.h>
#include <math.h>

#define NN 1024     // entities
#define HD 128      // hidden dim
#define NH 8        // heads
#define CH 16       // dim per head
#define NLAYERS 3

#define ALP 130     // k_edge_w al row stride
#define PBM 4       // k_proj rows per block
#define ABM 2       // k_edge_ab rows per block
#define QSC 0.36067376022224085f   // 0.25 * log2(e)

typedef __attribute__((ext_vector_type(8))) short short8;   // 8 bf16 (4 VGPR) MFMA operand
typedef __attribute__((ext_vector_type(4))) float f32x4;    // MFMA accumulator
typedef __attribute__((ext_vector_type(2))) float f32x2;    // packed-f32 pair (v_pk_*)

union FRG { uint4 u; short8 s; };

__device__ __forceinline__ float bf16_to_f32(unsigned short u) {
    union { unsigned int i; float f; } x; x.i = ((unsigned int)u) << 16; return x.f;
}
__device__ __forceinline__ unsigned short f32_to_bf16(float f) {
    union { float f; unsigned int i; } x; x.f = f;
    const unsigned int r = x.i + 0x7FFFu + ((x.i >> 16) & 1u);   // RNE
    return (unsigned short)(r >> 16);
}
__device__ __forceinline__ unsigned int fbits(float f) {
    union { float f; unsigned int i; } x; x.f = f; return x.i;
}

// ---------------- K1: a = x@W1[:128], b = x@W1[128:] + b1; by==0 also copies x -> xout ----------------
__global__ __launch_bounds__(256) void k_edge_ab(
        const float* __restrict__ x, const float* __restrict__ W1,
        const float* __restrict__ b1, float* __restrict__ a, float* __restrict__ b,
        float* __restrict__ xout) {
    __shared__ float xt[HD][ABM];
    __shared__ float red[2][ABM][HD];
    const int r0 = blockIdx.x * ABM;
    const int cb = blockIdx.y;           // 0 -> a, 1 -> b
    const int t  = threadIdx.x;
    {
        const float xv = x[(r0 + (t >> 7)) * HD + (t & 127)];
        xt[t & 127][t >> 7] = xv;
        if (cb == 0) xout[(r0 + (t >> 7)) * HD + (t & 127)] = xv;   // fused x init
    }
    __syncthreads();
    const int c = t & 127, g = t >> 7;
    const float* wp = W1 + cb * HD * HD + g * 64 * HD + c;
    const float* xp = &xt[g * 64][0];
    float a0 = 0.f, a1 = 0.f;
    #pragma unroll 8
    for (int kk = 0; kk < 64; ++kk) {
        const float wv = wp[kk * HD];
        const float2 xv = *(const float2*)&xp[kk * ABM];
        a0 = fmaf(xv.x, wv, a0);
        a1 = fmaf(xv.y, wv, a1);
    }
    red[g][0][c] = a0; red[g][1][c] = a1;
    __syncthreads();
    if (t < HD) {
        float* dst = cb ? b : a;
        const float bias = cb ? b1[t] : 0.f;
        #pragma unroll
        for (int r = 0; r < ABM; ++r)
            dst[(r0 + r) * HD + t] = red[0][r][t] + red[1][r][t] + bias;
    }
}

// ---------------- K2: wm[t][s] = bf16( sign(mask) * sigmoid(logit[s][t]) ); packed-f32 inner loop ----------------
__global__ __launch_bounds__(256) void k_edge_w(
        const float* __restrict__ a, const float* __restrict__ bb,
        const float* __restrict__ W2, const float* __restrict__ b2,
        unsigned short* __restrict__ wm) {
    __shared__ float al[32][ALP];
    __shared__ float bl[16][HD];
    const int t = threadIdx.x;
    const int s0 = blockIdx.x * 32, t0 = blockIdx.y * 16;
    for (int ii = t; ii < 2048; ii += 256) {
        const int row = ii >> 6, col = (ii & 63) * 2;
        *(float2*)&al[row][col] = *(const float2*)&a[(s0 + row) * HD + col];
    }
    for (int ii = t; ii < 512; ii += 256) {
        const int row = ii >> 5, col = (ii & 31) * 4;
        *(float4*)&bl[row][col] = *(const float4*)&bb[(t0 + row) * HD + col];
    }
    __syncthreads();
    const int s = t & 31, tt = t >> 5;
    const f32x2 zz = {0.f, 0.f};
    f32x2 acc0 = zz, acc1 = zz;
    #pragma unroll 2
    for (int h4 = 0; h4 < HD; h4 += 4) {
        const f32x2 w2a = {W2[h4],     W2[h4 + 1]};        // uniform -> s_load
        const f32x2 w2b = {W2[h4 + 2], W2[h4 + 3]};
        const f32x2 avA = *(const f32x2*)&al[s][h4];
        const f32x2 avB = *(const f32x2*)&al[s][h4 + 2];
        const f32x2 b0a = *(const f32x2*)&bl[tt][h4];
        const f32x2 b0b = *(const f32x2*)&bl[tt][h4 + 2];
        const f32x2 b1a = *(const f32x2*)&bl[tt + 8][h4];
        const f32x2 b1b = *(const f32x2*)&bl[tt + 8][h4 + 2];
        acc0 = __builtin_elementwise_fma(__builtin_elementwise_max(avA + b0a, zz), w2a, acc0);
        acc0 = __builtin_elementwise_fma(__builtin_elementwise_max(avB + b0b, zz), w2b, acc0);
        acc1 = __builtin_elementwise_fma(__builtin_elementwise_max(avA + b1a, zz), w2a, acc1);
        acc1 = __builtin_elementwise_fma(__builtin_elementwise_max(avB + b1b, zz), w2b, acc1);
    }
    const float bias = b2[0];
    const float l0 = acc0.x + acc0.y + bias, l1 = acc1.x + acc1.y + bias;
    const float w0 = 1.f / (1.f + __expf(-l0));
    const float w1 = 1.f / (1.f + __expf(-l1));
    wm[(t0 + tt    ) * NN + s0 + s] = f32_to_bf16((l0 > 0.f) ? w0 : -w0);   // sign encodes mask
    wm[(t0 + tt + 8) * NN + s0 + s] = f32_to_bf16((l1 > 0.f) ? w1 : -w1);
}

// ---------------- K3: projections qb,kb (bf16 [h][n][c]), vT (bf16 [h][c][n]) + skip (f32) ----------------
__global__ __launch_bounds__(256) void k_proj(
        const float* __restrict__ x,
        const float* __restrict__ Wq, const float* __restrict__ bq,
        const float* __restrict__ Wk, const float* __restrict__ bk,
        const float* __restrict__ Wv, const float* __restrict__ bv,
        const float* __restrict__ Wsk, const float* __restrict__ bsk,
        unsigned short* __restrict__ qb, unsigned short* __restrict__ kb,
        unsigned short* __restrict__ vT, float* __restrict__ skip) {
    __shared__ float xt[HD][PBM];
    __shared__ float red[2][PBM][HD];
    const int r0 = blockIdx.x * PBM;
    const int cb = blockIdx.y;           // 0..3 -> q,k,v,skip
    const int t  = threadIdx.x;
    {
        const int r = t >> 6, c2 = (t & 63) * 2;
        const float2 xv = *(const float2*)&x[(r0 + r) * HD + c2];
        xt[c2][r] = xv.x; xt[c2 + 1][r] = xv.y;
    }
    __syncthreads();
    const int c = t & 127, g = t >> 7;
    const float* W = (cb == 0) ? Wq : (cb == 1) ? Wk : (cb == 2) ? Wv : Wsk;
    const float* wp = W + g * 64 * HD + c;
    const float* xp = &xt[g * 64][0];
    float a0 = 0.f, a1 = 0.f, a2 = 0.f, a3 = 0.f;
    #pragma unroll 8
    for (int kk = 0; kk < 64; ++kk) {
        const float wv = wp[kk * HD];
        const float4 xv = *(const float4*)&xp[kk * PBM];
        a0 = fmaf(xv.x, wv, a0);
        a1 = fmaf(xv.y, wv, a1);
        a2 = fmaf(xv.z, wv, a2);
        a3 = fmaf(xv.w, wv, a3);
    }
    red[g][0][c] = a0; red[g][1][c] = a1; red[g][2][c] = a2; red[g][3][c] = a3;
    __syncthreads();
    if (t < HD) {
        const float* bptr = (cb == 0) ? bq : (cb == 1) ? bk : (cb == 2) ? bv : bsk;
        const float bias = bptr[t];
        const int h = t >> 4, ch = t & 15;
        #pragma unroll
        for (int r = 0; r < PBM; ++r) {
            const float val = red[0][r][t] + red[1][r][t] + bias;
            const int row = r0 + r;
            if (cb == 3) {
                skip[row * HD + t] = val;
            } else if (cb == 0) {
                qb[(h * NN + row) * CH + ch] = f32_to_bf16(val);
            } else if (cb == 1) {
                kb[(h * NN + row) * CH + ch] = f32_to_bf16(val);
            } else {
                vT[(h * CH + ch) * NN + row] = f32_to_bf16(val);   // transposed for PV B-frag
            }
        }
    }
}

// ---------------- K4: MFMA flash attention; 8 waves x 128-j strips (4 waves/SIMD) ----------------
// grid (NN/16, NH), 512 threads. Per 16-j tile: S^T = mfma(K_rows, Q) -> lane holds s at
// (i = lane&15, j = 4*(lane>>4)+reg). Two-pass softmax; PV = mfma(P, V) with P shfl'd
// into A-layout and V read from vT.
__global__ __launch_bounds__(512) void k_attn(
        const unsigned short* __restrict__ qb, const unsigned short* __restrict__ kb,
        const unsigned short* __restrict__ vT, const float* __restrict__ skip,
        const unsigned short* __restrict__ wm, const float* __restrict__ We,
        float* __restrict__ x) {
    __shared__ float mrg[8][16][20];     // 10 KB: per-wave partials {m,sum,aw,o[16]}
    const int i0 = blockIdx.x * 16;
    const int h  = blockIdx.y;
    const int t  = threadIdx.x;
    const int w  = t >> 6, l = t & 63;
    const int li = l & 15, G = l >> 4;

    // Q B-frag (persistent): B[k][i]: col=lane&15=i, k=8G+e (k>=16 -> zero)
    FRG qf;
    if (G < 2) qf.u = *(const uint4*)(qb + ((size_t)h * NN + i0 + li) * CH + 8 * G);
    else       qf.u = make_uint4(0, 0, 0, 0);

    // qe[i] = dot(q[i], We[h]) * QSC   (i = li)
    float qe = 0.f;
    {
        const uint4 qa = *(const uint4*)(qb + ((size_t)h * NN + i0 + li) * CH);
        const uint4 qb2 = *(const uint4*)(qb + ((size_t)h * NN + i0 + li) * CH + 8);
        const unsigned int qd[8] = {qa.x, qa.y, qa.z, qa.w, qb2.x, qb2.y, qb2.z, qb2.w};
        #pragma unroll
        for (int d2 = 0; d2 < 8; ++d2) {
            qe = fmaf(bf16_to_f32((unsigned short)(qd[d2] & 0xffff)), We[h * CH + 2 * d2], qe);
            qe = fmaf(bf16_to_f32((unsigned short)(qd[d2] >> 16)),    We[h * CH + 2 * d2 + 1], qe);
        }
        qe *= QSC;
    }
    const unsigned short* wrow = wm + (size_t)(i0 + li) * NN;
    const int j0s = w * 128;             // this wave's j strip

    // ---- pass 1: 8 QK^T tiles; stash logits; track row max (per-lane: fixed i) ----
    float m = -1e30f;
    float sst[8][4];
    #pragma unroll
    for (int tt = 0; tt < 8; ++tt) {
        const int j0 = j0s + tt * 16;
        FRG kf;
        if (G < 2) kf.u = *(const uint4*)(kb + ((size_t)h * NN + j0 + li) * CH + 8 * G);
        else       kf.u = make_uint4(0, 0, 0, 0);
        f32x4 d = __builtin_amdgcn_mfma_f32_16x16x32_bf16(kf.s, qf.s, (f32x4){0.f, 0.f, 0.f, 0.f}, 0, 0, 0);
        const uint2 wmu = *(const uint2*)(wrow + j0 + 4 * G);
        const unsigned short wu[4] = {(unsigned short)(wmu.x & 0xffff), (unsigned short)(wmu.x >> 16),
                                      (unsigned short)(wmu.y & 0xffff), (unsigned short)(wmu.y >> 16)};
        #pragma unroll
        for (int rg = 0; rg < 4; ++rg) {
            const float wv = bf16_to_f32(wu[rg]);               // sign = mask; wv>0 -> wa = wv
            const float sv = (wv > 0.f) ? fmaf(qe, wv, d[rg] * QSC) : -1e30f;
            sst[tt][rg] = sv;
            m = fmaxf(m, sv);
        }
    }
    m = fmaxf(m, __shfl_xor(m, 16));
    m = fmaxf(m, __shfl_xor(m, 32));     // final row max for i = li over this strip

    // ---- pass 2: p = exp2(s-m); sum/aw; P->bf16 -> shfl to A-layout -> PV mfma ----
    f32x4 oc = {0.f, 0.f, 0.f, 0.f};
    float sum = 0.f, aw = 0.f;
    const int srcA = (G & 1) * 32 + li;
    const int srcB = srcA + 16;
    #pragma unroll
    for (int cc = 0; cc < 4; ++cc) {
        unsigned int pk[4];              // {tile0:j01, tile0:j23, tile1:j01, tile1:j23}
        #pragma unroll
        for (int hh = 0; hh < 2; ++hh) {
            const int tt = 2 * cc + hh;
            const uint2 wmu = *(const uint2*)(wrow + j0s + tt * 16 + 4 * G);
            const unsigned short wu[4] = {(unsigned short)(wmu.x & 0xffff), (unsigned short)(wmu.x >> 16),
                                          (unsigned short)(wmu.y & 0xffff), (unsigned short)(wmu.y >> 16)};
            float p[4];
            #pragma unroll
            for (int rg = 0; rg < 4; ++rg) {
                p[rg] = __builtin_amdgcn_exp2f(sst[tt][rg] - m);   // masked underflows to 0
                sum += p[rg];
                aw = fmaf(p[rg], fabsf(bf16_to_f32(wu[rg])), aw);
            }
            pk[2 * hh]     = (fbits(p[0]) >> 16) | (fbits(p[1]) & 0xffff0000u);   // truncation pack
            pk[2 * hh + 1] = (fbits(p[2]) >> 16) | (fbits(p[3]) & 0xffff0000u);
        }
        // gather A-frag: lane needs p at (i=li, j32 = 8G+e)
        const unsigned int a0 = (unsigned int)__shfl((int)pk[0], srcA);
        const unsigned int a1 = (unsigned int)__shfl((int)pk[1], srcA);
        const unsigned int a2 = (unsigned int)__shfl((int)pk[0], srcB);
        const unsigned int a3 = (unsigned int)__shfl((int)pk[1], srcB);
        const unsigned int b0 = (unsigned int)__shfl((int)pk[2], srcA);
        const unsigned int b1 = (unsigned int)__shfl((int)pk[3], srcA);
        const unsigned int b2 = (unsigned int)__shfl((int)pk[2], srcB);
        const unsigned int b3 = (unsigned int)__shfl((int)pk[3], srcB);
        FRG pf;
        pf.u.x = (G >= 2) ? b0 : a0;
        pf.u.y = (G >= 2) ? b1 : a1;
        pf.u.z = (G >= 2) ? b2 : a2;
        pf.u.w = (G >= 2) ? b3 : a3;
        FRG vf;                          // B[k=j][c]: col=li=c, k=8G+e -> uint4 from vT
        vf.u = *(const uint4*)(vT + ((size_t)h * CH + li) * NN + j0s + cc * 32 + 8 * G);
        oc = __builtin_amdgcn_mfma_f32_16x16x32_bf16(pf.s, vf.s, oc, 0, 0, 0);
    }
    sum += __shfl_xor(sum, 16); sum += __shfl_xor(sum, 32);
    aw  += __shfl_xor(aw, 16);  aw  += __shfl_xor(aw, 32);

    // dump wave partials: m/sum/aw keyed by i=li (lanes G==0); out keyed by i=4G+rg, c=li
    if (l < 16) { mrg[w][l][0] = m; mrg[w][l][1] = sum; mrg[w][l][2] = aw; }
    #pragma unroll
    for (int rg = 0; rg < 4; ++rg) mrg[w][4 * G + rg][3 + li] = oc[rg];
    __syncthreads();

    // final combine: thread (r2, c) merges the 8 wave-partials and writes x
    if (t < 256) {
        const int r2 = t >> 4, c = t & 15;
        float ms = -1e30f;
        #pragma unroll
        for (int k = 0; k < 8; ++k) ms = fmaxf(ms, mrg[k][r2][0]);
        float sums = 0.f, aws = 0.f, ocm = 0.f;
        #pragma unroll
        for (int k = 0; k < 8; ++k) {
            const float fk = __builtin_amdgcn_exp2f(mrg[k][r2][0] - ms);
            sums = fmaf(fk, mrg[k][r2][1], sums);
            aws  = fmaf(fk, mrg[k][r2][2], aws);
            ocm  = fmaf(fk, mrg[k][r2][3 + c], ocm);
        }
        const float inv = (ms > -1e29f) ? 1.f / sums : 0.f;   // all-masked row -> 0
        const int idx = (i0 + r2) * HD + h * CH + c;
        x[idx] = x[idx] + skip[idx] + ocm * inv + (aws * inv) * We[h * CH + c];
    }
}

// ---------------- launch ----------------
extern "C" void kernel_launch(void* const* d_in, const int* in_sizes, int n_in,
                              void* d_out, int out_size, void* d_ws, size_t ws_size,
                              hipStream_t stream) {
    const float* ent = (const float*)d_in[2];
    const float* W1  = (const float*)d_in[3];
    const float* b1  = (const float*)d_in[4];
    const float* W2  = (const float*)d_in[5];
    const float* b2  = (const float*)d_in[6];
    const float* Wq  = (const float*)d_in[7];
    const float* bq  = (const float*)d_in[8];
    const float* Wk  = (const float*)d_in[9];
    const float* bk  = (const float*)d_in[10];
    const float* Wv  = (const float*)d_in[11];
    const float* bv  = (const float*)d_in[12];
    const float* We  = (const float*)d_in[13];
    const float* Ws  = (const float*)d_in[14];
    const float* bs  = (const float*)d_in[15];

    unsigned short* wm = (unsigned short*)d_ws;   // [1024][1024] bf16, sign = mask (2 MB)
    float* a  = (float*)(wm + (size_t)NN * NN);   // f32 scratch for edge phase
    float* bf = a + NN * HD;
    float* sk = bf + NN * HD;
    unsigned short* qb = (unsigned short*)(sk + NN * HD);   // [8][1024][16] bf16
    unsigned short* kb = qb + NN * HD;                      // [8][1024][16] bf16
    unsigned short* vT = kb + NN * HD;                      // [8][16][1024] bf16 (transposed)
    float* x  = (float*)d_out;                    // running entity state

    k_edge_ab<<<dim3(NN / ABM, 2), 256, 0, stream>>>(ent, W1, b1, a, bf, x);
    k_edge_w<<<dim3(32, 64), 256, 0, stream>>>(a, bf, W2, b2, wm);

    for (int l = 0; l < NLAYERS; ++l) {
        k_proj<<<dim3(NN / PBM, 4), 256, 0, stream>>>(x,
            Wq + l * HD * HD, bq + l * HD, Wk + l * HD * HD, bk + l * HD,
            Wv + l * HD * HD, bv + l * HD, Ws + l * HD * HD, bs + l * HD,
            qb, kb, vT, sk);
        k_attn<<<dim3(NN / 16, NH), 512, 0, stream>>>(qb, kb, vT, sk, wm, We + l * HD, x);
    }
}